// Round 1
// baseline (132.367 us; speedup 1.0000x reference)
//
#include <hip/hip_runtime.h>
#include <math.h>

#define B_DIM 256
#define M_DIM 4096
#define EPSV 1e-7f
#define THREADS 1024
#define NWAVES (THREADS / 64)          // 16 waves/block
#define WAVE_ELEMS (M_DIM / NWAVES)    // 256 elements per wave
#define SUB 64                         // elements per sub-chunk (1 per lane)
#define NSUB (WAVE_ELEMS / SUB)        // 4 sub-chunks per wave
#define SUB_F4 (SUB * 9 / 4)           // 144 float4 per array per sub-chunk
#define WAVE_F4 (WAVE_ELEMS * 9 / 4)   // 576 float4 per array per wave slice
#define ROW_F4 (M_DIM * 9 / 4)         // 9216 float4 per array per row
#define RECON_F4_PER_BLOCK ((B_DIM * 128 * 128 / 4) / B_DIM)  // 4096

// ws layout (floats):
//   [0 .. 2048)  per-block partials: 256 blocks x 8 {coord,width,val,nval,cont,recon}

// Per-wave named-register prefetch: NOTHING addressable, so no scratch.
// Each wave owns elements [wave*256, wave*256+256) of its row and stages
// 64-element sub-chunks through its PRIVATE 4608 B LDS region — no
// block-wide barriers in the streaming phase (DS ops are in-order per wave).
#define LOADW(cc, P0, P1, P2, T0, T1, T2)                              \
    do {                                                               \
        const float4* pc_ = pw + (cc) * SUB_F4;                        \
        const float4* tc_ = tw + (cc) * SUB_F4;                        \
        P0 = pc_[lane];      T0 = tc_[lane];                           \
        P1 = pc_[lane + 64]; T1 = tc_[lane + 64];                      \
        if (lane < 16) { P2 = pc_[lane + 128]; T2 = tc_[lane + 128]; } \
    } while (0)

#define STOREW(P0, P1, P2, T0, T1, T2)                                 \
    do {                                                               \
        float4* sp_ = (float4*)(s_stage[wave]);                        \
        float4* st_ = (float4*)(s_stage[wave] + 576);                  \
        sp_[lane] = P0;      st_[lane] = T0;                           \
        sp_[lane + 64] = P1; st_[lane + 64] = T1;                      \
        if (lane < 16) { sp_[lane + 128] = P2; st_[lane + 128] = T2; } \
    } while (0)

__global__ void __launch_bounds__(THREADS)
__attribute__((amdgpu_waves_per_eu(4, 4)))
fused_loss_kernel(
    const float4* __restrict__ pred4, const float4* __restrict__ tgt4,
    const float4* __restrict__ rec4, const float4* __restrict__ img4,
    float* __restrict__ blk_out)
{
    __shared__ float s_stage[NWAVES][1152];            // 72 KB: per-wave {pred 576, tgt 576}
    __shared__ float s_p4[M_DIM];                      // 16 KB
    __shared__ float s_p5[M_DIM];                      // 16 KB
    __shared__ unsigned long long s_words[M_DIM / 64]; // 512 B
    __shared__ float s_red[16][6];

    const int b    = blockIdx.x;
    const int t    = threadIdx.x;
    const int lane = t & 63;
    const int wave = t >> 6;

    // this wave's slice of the row, in float4 units
    const float4* pw = pred4 + (size_t)b * ROW_F4 + wave * WAVE_F4;
    const float4* tw = tgt4  + (size_t)b * ROW_F4 + wave * WAVE_F4;

    float coord_s = 0.f, width_s = 0.f, val_s = 0.f, nval_s = 0.f;

    // consume sub-chunk c from this wave's private LDS stage; lane owns one element
    auto consume = [&](int c) {
        const float* pe = s_stage[wave] + lane * 9;        // stride 9 coprime to 32 banks
        const float* te = s_stage[wave] + 576 + lane * 9;
        float p0 = pe[0], p1 = pe[1], p2 = pe[2], p3 = pe[3], p4 = pe[4],
              p5 = pe[5], p6 = pe[6], p7 = pe[7], p8 = pe[8];
        float t0 = te[0], t1 = te[1], t2 = te[2], t3 = te[3], t4 = te[4],
              t5 = te[5], t6 = te[6], t7 = te[7], t8 = te[8];

        bool valid = (t8 > 0.5f);
        float fm = valid ? 1.f : 0.f;
        coord_s += fm * (fabsf(p0 - t0) + fabsf(p1 - t1) + fabsf(p2 - t2) +
                         fabsf(p3 - t3) + fabsf(p4 - t4) + fabsf(p5 - t5));
        width_s += fm * (fabsf(p6 - t6) + fabsf(p7 - t7));
        nval_s  += fm;

        float pc8 = fminf(fmaxf(p8, EPSV), 1.0f - EPSV);
        val_s += -(t8 * __logf(pc8) + (1.0f - t8) * __logf(1.0f - pc8));

        const int m = wave * WAVE_ELEMS + c * SUB + lane;
        s_p4[m] = p4;
        s_p5[m] = p5;
        unsigned long long bal = __ballot(valid);
        if (lane == 0) s_words[wave * NSUB + c] = bal;     // m>>6 == wave*4+c exactly
    };

    float4 PA0, PA1, PA2, TA0, TA1, TA2;
    float4 PB0, PB1, PB2, TB0, TB1, TB2;

    // sub-chunk 0 loads in flight while recon computes
    LOADW(0, PA0, PA1, PA2, TA0, TA1, TA2);

    // ---- reconstruction MSE: this block's contiguous 1/256 slice ----
    float recon_s = 0.f;
    {
        const float4* rb = rec4 + (size_t)b * RECON_F4_PER_BLOCK;
        const float4* ib = img4 + (size_t)b * RECON_F4_PER_BLOCK;
        #pragma unroll
        for (int i = 0; i < RECON_F4_PER_BLOCK / THREADS; ++i) {   // 4 iters
            int idx = i * THREADS + t;
            float4 r = rb[idx]; float4 m = ib[idx];
            float d0 = r.x - m.x, d1 = r.y - m.y, d2 = r.z - m.z, d3 = r.w - m.w;
            recon_s += d0 * d0 + d1 * d1 + d2 * d2 + d3 * d3;
        }
    }

    // ---- per-wave 1-deep register-prefetch pipeline: ZERO barriers here ----
    STOREW(PA0, PA1, PA2, TA0, TA1, TA2);
    LOADW(1, PB0, PB1, PB2, TB0, TB1, TB2);
    consume(0);

    STOREW(PB0, PB1, PB2, TB0, TB1, TB2);
    LOADW(2, PA0, PA1, PA2, TA0, TA1, TA2);
    consume(1);

    STOREW(PA0, PA1, PA2, TA0, TA1, TA2);
    LOADW(3, PB0, PB1, PB2, TB0, TB1, TB2);
    consume(2);

    STOREW(PB0, PB1, PB2, TB0, TB1, TB2);
    consume(3);

    __syncthreads();   // the ONLY block-wide barrier before reductions

    // ---- continuity: next-valid bit-scan over full row ----
    float cont_s = 0.f;
    #pragma unroll
    for (int p = 0; p < 4; ++p) {
        const int m   = p * 1024 + t;
        const int w   = m >> 6;
        const int bit = m & 63;
        unsigned long long wv = s_words[w];
        if ((wv >> bit) & 1ULL) {
            unsigned long long mask = wv & ((bit == 63) ? 0ULL : (~0ULL << (bit + 1)));
            int nxt = -1;
            if (mask) {
                nxt = (w << 6) + __builtin_ctzll(mask);
            } else {
                for (int w2 = w + 1; w2 < (M_DIM / 64); ++w2) {
                    unsigned long long mw = s_words[w2];
                    if (mw) { nxt = (w2 << 6) + __builtin_ctzll(mw); break; }
                }
            }
            if (nxt >= 0) {
                cont_s += 0.5f * (fabsf(s_p4[m] - s_p4[nxt]) +
                                  fabsf(s_p5[m] - s_p5[nxt]));
            }
        }
    }

    // ---- block reduction of 6 partials; per-block slot write (no atomics) ----
    float vals[6] = {coord_s, width_s, val_s, nval_s, cont_s, recon_s};
    #pragma unroll
    for (int i = 0; i < 6; ++i) {
        float v = vals[i];
        #pragma unroll
        for (int off = 32; off > 0; off >>= 1) v += __shfl_down(v, off, 64);
        vals[i] = v;
    }
    if (lane == 0) {
        #pragma unroll
        for (int i = 0; i < 6; ++i) s_red[wave][i] = vals[i];
    }
    __syncthreads();
    if (t == 0) {
        float acc[6] = {0.f, 0.f, 0.f, 0.f, 0.f, 0.f};
        for (int wv = 0; wv < 16; ++wv)
            #pragma unroll
            for (int i = 0; i < 6; ++i) acc[i] += s_red[wv][i];
        float* r = blk_out + b * 8;
        #pragma unroll
        for (int i = 0; i < 6; ++i) r[i] = acc[i];
    }
}

__global__ __launch_bounds__(256) void finalize_kernel(
    const float* __restrict__ ws, float* __restrict__ out)
{
    const int t = threadIdx.x;
    const float* rb = ws + t * 8;
    float v[6];
    #pragma unroll
    for (int i = 0; i < 6; ++i) v[i] = rb[i];

    __shared__ float sred[4][6];
    int lane = t & 63, wave = t >> 6;
    #pragma unroll
    for (int i = 0; i < 6; ++i) {
        float x = v[i];
        #pragma unroll
        for (int off = 32; off > 0; off >>= 1) x += __shfl_down(x, off, 64);
        v[i] = x;
    }
    if (lane == 0)
        #pragma unroll
        for (int i = 0; i < 6; ++i) sred[wave][i] = v[i];
    __syncthreads();
    if (t == 0) {
        double a[6];
        #pragma unroll
        for (int i = 0; i < 6; ++i)
            a[i] = (double)sred[0][i] + (double)sred[1][i] +
                   (double)sred[2][i] + (double)sred[3][i];
        double coord_num = a[0], width_num = a[1], val_sum = a[2],
               nv = a[3], cont = a[4], recon = a[5];

        double coord = (nv > 0.0) ? coord_num / fmax(nv * 6.0, 1.0) : 0.0;
        double width = (nv > 0.0) ? width_num / fmax(nv * 2.0, 1.0) : 0.0;
        double validity = val_sum / ((double)B_DIM * (double)M_DIM);
        double contl    = cont / (double)B_DIM;
        double reconl   = recon / ((double)B_DIM * 128.0 * 128.0);

        out[0] = (float)(coord + width + 2.0 * validity +
                         0.2 * contl + 0.1 * reconl);
    }
}

extern "C" void kernel_launch(void* const* d_in, const int* in_sizes, int n_in,
                              void* d_out, int out_size, void* d_ws, size_t ws_size,
                              hipStream_t stream) {
    const float* pred = (const float*)d_in[0];
    const float* tgt  = (const float*)d_in[1];
    const float* rec  = (const float*)d_in[2];
    const float* img  = (const float*)d_in[3];
    float* ws = (float*)d_ws;

    fused_loss_kernel<<<B_DIM, THREADS, 0, stream>>>(
        (const float4*)pred, (const float4*)tgt,
        (const float4*)rec, (const float4*)img, ws);
    finalize_kernel<<<1, 256, 0, stream>>>(ws, (float*)d_out);
}